// Round 14
// baseline (944.153 us; speedup 1.0000x reference)
//
#include <hip/hip_runtime.h>

// ---------------------------------------------------------------------------
// VariLengthInputLayer: fused multi-modality QKV + 4x4 attention + FC + LN
//   K1: merged f32->bf16 convert (one dispatch; nt input loads)
//   K2: grouped QKV GEMM, 256x256 tile, BK=64, **16 waves x 64x64 acc**
//       (1024 thr, ~110 VGPR -> 4 waves/SIMD; occupancy feeds MFMA pipe),
//       2-phase cert loop, counted vmcnt(3)/vmcnt(1), verified XOR swizzle,
//       2D XCD-chunked block mapping
//   K3: attention: 4 (b,h) pairs per wave, 16-lane groups (nt qkv loads)
//   K4: FC GEMM (same engine) + bias + residual -> pre-LN bf16
//   K5: LayerNorm(1024, bf16 in) -> d_out
// ---------------------------------------------------------------------------

typedef unsigned short u16;
typedef short short8 __attribute__((ext_vector_type(8)));
typedef unsigned short u16x4 __attribute__((ext_vector_type(4)));
typedef float f32x4 __attribute__((ext_vector_type(4)));

__device__ __forceinline__ u16 f2bf(float f) {
  unsigned u = __builtin_bit_cast(unsigned, f);
  u += 0x7FFFu + ((u >> 16) & 1u);  // RNE
  return (u16)(u >> 16);
}
__device__ __forceinline__ float bf2f(u16 s) {
  return __builtin_bit_cast(float, ((unsigned)s) << 16);
}

__device__ __forceinline__ void gload16(const u16* g, u16* l) {
  __builtin_amdgcn_global_load_lds(
      (const __attribute__((address_space(1))) void*)g,
      (__attribute__((address_space(3))) void*)l, 16, 0, 0);
}

#define CFENCE asm volatile("" ::: "memory")

// --------------------------- merged f32 -> bf16 convert --------------------
struct CArgs {
  const float* src[14];
  unsigned long dst[14];
  int blk0[14];
  int n4[14];
};

__global__ __launch_bounds__(256) void convall(CArgs a, u16* __restrict__ wsb) {
  int blk = blockIdx.x;
  int s = 0;
#pragma unroll
  for (int i = 1; i < 14; ++i) s = (blk >= a.blk0[i]) ? i : s;
  int li = (blk - a.blk0[s]) * 256 + threadIdx.x;
  if (li < a.n4[s]) {
    f32x4 v = __builtin_nontemporal_load((const f32x4*)a.src[s] + li);
    u16x4 o;
    o.x = f2bf(v.x); o.y = f2bf(v.y); o.z = f2bf(v.z); o.w = f2bf(v.w);
    *((u16x4*)(wsb + a.dst[s]) + li) = o;  // plain store: GEMM re-reads this
  }
}

// --------------------- 256^2 GEMM, 16 waves, 2-phase cert ------------------
// C = A @ B^T.  A [M x K] bf16 (row stride lda), B [N x K] bf16 (K contig).
// 1024 threads = 16 waves (4M x 4N); per-wave 64x64 out (acc = 64 VGPR ->
// ~110 VGPR total -> 4 waves/SIMD; the MFMA pipe needs 2048 cy/CU per K-tile
// and 4 waves/SIMD keep it fed through barrier/lgkm gaps).
// LDS 128 KiB: buf(t&1) { A: 2 halves (row bit6), B: 2 halves (col bit5) }.
//   16B-chunk swizzle pc = kc ^ (rw&7); staging writes linear LDS dest from
//   inverse-swizzled global source; reads apply the same XOR (verified
//   conflict-free R8/R11/R13: SQ_LDS_BANK_CONFLICT = 0).
// Wave wm owns rows wm*64..+63 = LDS A-half (wm&1), local base (wm>>1)*64.
// Wave wn owns cols wn*64..+63 = B-half0 cols wn*64+0..31, half1 +32..63.
// Per K-tile t (1 stage-half = 16KB = 1 gload16/thread):
//   P1: read A(own half)[8] + B-L[4]; stage A-L,A-H,B-L(t+1) [3]; bar;
//       lgkm0; 16 MFMA (acc cols 0-1); vmcnt(3) certs B-H(t); bar
//   P2: read B-H[4]; stage B-H(t+1) [1]; bar; lgkm0; 16 MFMA (cols 2-3);
//       vmcnt(1) certs A-L,A-H,B-L(t+1); bar
// vmcnt BEFORE the trailing barrier = cross-wave cert.
// MODE 0: grouped QKV (seg->modality, LPT), C -> qkv bf16 ldc 12288
// MODE 1: FC, C -> bf16 pre = acc + bias + residual(qkv v-slice), ldc 1024
template <int MODE>
__global__ __launch_bounds__(1024, 4)
void gemm16(const u16* __restrict__ Abase, int lda,
            const u16* __restrict__ Wbase, u16* __restrict__ Cq,
            u16* __restrict__ Cpre, const float* __restrict__ bias,
            const u16* __restrict__ resid) {
  __shared__ __align__(16) u16 lds[65536];  // 128 KiB

  const int tid = threadIdx.x;
  const int w = tid >> 6, lane = tid & 63;
  const int lr = lane & 15, lk = lane >> 4;
  const int wm = w >> 2, wn = w & 3;      // 4x4 wave grid

  int K, nt, bx, by, coff;
  const u16 *A, *B;
  if (MODE == 0) {
    int seg = blockIdx.x / 384;  // LPT: longest K first
    int r = blockIdx.x % 384;
    // 2D XCD chunking: xcd = r%8 (hw round-robin, 384%8==0 bijective);
    // each XCD: 16by x 3bx chunk, bx fastest (A panels XCD-L2-resident)
    int xcd = r & 7;
    int slot = r >> 3;
    by = (xcd >> 2) * 16 + slot / 3;
    bx = (xcd & 3) * 3 + slot % 3;
    K = 4096 >> seg; nt = 64 >> seg;
    int xo, wo, mod;
    switch (seg) {
      case 0:  xo = 3584; wo = 11010048; mod = 3; break;
      case 1:  xo = 0;    wo = 0;        mod = 0; break;
      case 2:  xo = 2048; wo = 6291456;  mod = 1; break;
      default: xo = 3072; wo = 9437184;  mod = 2; break;
    }
    coff = mod * 3072;
    A = Abase + xo;
    B = Wbase + wo;
  } else {
    int xcd = blockIdx.x & 7;
    int slot = blockIdx.x >> 3;  // 0..63 (512%8==0 bijective)
    by = xcd * 16 + (slot >> 2);
    bx = slot & 3;
    K = 1024; nt = 16; coff = 0;
    A = Abase; B = Wbase;
  }
  const size_t brow = (size_t)by * 256;
  const int bcol = bx * 256;
  const u16* Ab = A + brow * (size_t)lda;
  const u16* Bb = B + (size_t)bcol * (size_t)K;

  f32x4 acc[4][4];
#pragma unroll
  for (int i = 0; i < 4; ++i)
#pragma unroll
    for (int j = 0; j < 4; ++j) acc[i][j] = (f32x4){0.f, 0.f, 0.f, 0.f};

  // ---- staging: 1 half = 16 KB = 1 gload16/thread, linear LDS dest ----
  auto stageA = [&](int p, int half) {
    const int base = (p & 1) * 65536 + half * 16384;  // bytes
    const int k0 = p * 64;
    int s = tid * 16;                             // byte slot in half
    int rw = s >> 7;                              // row-within-half 0..127
    int ck = ((s >> 4) & 7) ^ (rw & 7);           // logical k-chunk here
    int row = (rw & 63) + ((rw >> 6) << 7) + half * 64;  // tile row
    gload16(Ab + (size_t)row * lda + k0 + ck * 8, &lds[(base + s) >> 1]);
  };
  auto stageB = [&](int p, int half) {
    const int base = (p & 1) * 65536 + 32768 + half * 16384;
    const int k0 = p * 64;
    int s = tid * 16;
    int rw = s >> 7;
    int ck = ((s >> 4) & 7) ^ (rw & 7);
    int col = (rw & 31) + ((rw >> 5) << 6) + half * 32;  // tile col (B row)
    gload16(Bb + (size_t)col * (size_t)K + k0 + ck * 8, &lds[(base + s) >> 1]);
  };

  // ---- fragment reads (swizzled); wave reads its OWN A-half ----
  const int haA = wm & 1;          // which LDS A-half holds this wave's rows
  const int rbA = (wm >> 1) * 64;  // local row base within that half
  auto ldA = [&](int t, short8* dst) {  // dst[mi*2+ks], 8 frags
    const u16* lp = lds + (((t & 1) * 65536 + haA * 16384) >> 1);
#pragma unroll
    for (int mi = 0; mi < 4; ++mi) {
      int rw = rbA + mi * 16 + lr;
#pragma unroll
      for (int ks = 0; ks < 2; ++ks) {
        int pc = (ks * 4 + lk) ^ (rw & 7);
        dst[mi * 2 + ks] = *(const short8*)(lp + rw * 64 + pc * 8);
      }
    }
  };
  auto ldB = [&](int t, int half, short8* dst) {  // dst[ni*2+ks], 4 frags
    const u16* lp = lds + (((t & 1) * 65536 + 32768 + half * 16384) >> 1);
#pragma unroll
    for (int ni = 0; ni < 2; ++ni) {
      int rw = wn * 32 + ni * 16 + lr;
#pragma unroll
      for (int ks = 0; ks < 2; ++ks) {
        int pc = (ks * 4 + lk) ^ (rw & 7);
        dst[ni * 2 + ks] = *(const short8*)(lp + rw * 64 + pc * 8);
      }
    }
  };

  short8 af[8], bl[4], bh[4];
  auto MQ = [&](short8* b, int no) {  // 16 MFMA: all mi x 2 ni x 2 ks
#pragma unroll
    for (int mi = 0; mi < 4; ++mi)
#pragma unroll
      for (int ni = 0; ni < 2; ++ni) {
        acc[mi][no + ni] = __builtin_amdgcn_mfma_f32_16x16x32_bf16(
            af[mi * 2 + 0], b[ni * 2 + 0], acc[mi][no + ni], 0, 0, 0);
        acc[mi][no + ni] = __builtin_amdgcn_mfma_f32_16x16x32_bf16(
            af[mi * 2 + 1], b[ni * 2 + 1], acc[mi][no + ni], 0, 0, 0);
      }
  };

  // prologue: stage tile 0 as A-L, A-H, B-L, B-H; cert first 3 (B-H flies)
  stageA(0, 0); stageA(0, 1); stageB(0, 0); stageB(0, 1);
  asm volatile("s_waitcnt vmcnt(1)" ::: "memory");
  __builtin_amdgcn_s_barrier();
  CFENCE;

#pragma unroll 1
  for (int t = 0; t < nt; ++t) {
    const bool more = (t + 1 < nt);
    // ---- P1: A(own)[8] + B-L[4] reads; stage A-L,A-H,B-L(t+1); MFMA lo ----
    ldA(t, af);
    ldB(t, 0, bl);
    if (more) { stageA(t + 1, 0); stageA(t + 1, 1); stageB(t + 1, 0); }
    CFENCE;
    __builtin_amdgcn_s_barrier();
    asm volatile("s_waitcnt lgkmcnt(0)" ::: "memory");
    __builtin_amdgcn_sched_barrier(0);
    __builtin_amdgcn_s_setprio(1);
    MQ(bl, 0);
    __builtin_amdgcn_s_setprio(0);
    CFENCE;
    // cert B-H(t) (oldest outstanding); keep t+1's 3 stages in flight
    if (more) asm volatile("s_waitcnt vmcnt(3)" ::: "memory");
    else      asm volatile("s_waitcnt vmcnt(0)" ::: "memory");
    __builtin_amdgcn_s_barrier();
    CFENCE;
    // ---- P2: B-H[4] reads; stage B-H(t+1); MFMA hi ----
    ldB(t, 1, bh);
    if (more) stageB(t + 1, 1);
    CFENCE;
    __builtin_amdgcn_s_barrier();
    asm volatile("s_waitcnt lgkmcnt(0)" ::: "memory");
    __builtin_amdgcn_sched_barrier(0);
    __builtin_amdgcn_s_setprio(1);
    MQ(bh, 2);
    __builtin_amdgcn_s_setprio(0);
    CFENCE;
    if (more) {
      // cert A-L,A-H,B-L(t+1): oldest 3 of 4 outstanding
      asm volatile("s_waitcnt vmcnt(1)" ::: "memory");
      __builtin_amdgcn_s_barrier();
      CFENCE;
    }
  }

  // epilogue: C/D layout col=lane&15, row=(lane>>4)*4+j
  if (MODE == 0) {
#pragma unroll
    for (int mi = 0; mi < 4; ++mi)
#pragma unroll
      for (int nj = 0; nj < 4; ++nj) {
        const int c = coff + bcol + wn * 64 + nj * 16 + lr;
#pragma unroll
        for (int j = 0; j < 4; ++j) {
          size_t r = brow + wm * 64 + mi * 16 + lk * 4 + j;
          Cq[r * 12288 + c] = f2bf(acc[mi][nj][j]);
        }
      }
  } else {
#pragma unroll
    for (int mi = 0; mi < 4; ++mi)
#pragma unroll
      for (int nj = 0; nj < 4; ++nj) {
        const int c = bcol + wn * 64 + nj * 16 + lr;
        const float bs = bias[c];
#pragma unroll
        for (int j = 0; j < 4; ++j) {
          size_t r = brow + wm * 64 + mi * 16 + lk * 4 + j;
          size_t ridx = (r >> 2) * 12288 + (r & 3) * 3072 + 2048 + c;
          Cpre[r * 1024 + c] = f2bf(acc[mi][nj][j] + bs + bf2f(resid[ridx]));
        }
      }
  }
}

// --------------------------- attention ------------------------------------
__global__ __launch_bounds__(256) void attn_k(const u16* __restrict__ qkv,
                                              u16* __restrict__ ctxb,
                                              float* __restrict__ attn_out) {
  const int tid = threadIdx.x;
  const int l = tid & 63;
  const int wg = blockIdx.x * 4 + (tid >> 6);
  const int b = wg >> 2;
  const int h0 = (wg & 3) << 2;
  const size_t base = (size_t)b * 12288 + h0 * 64 + l * 4;

  float q[4][4], k[4][4], v[4][4];
#pragma unroll
  for (int m = 0; m < 4; ++m) {
    u16x4 uq = __builtin_nontemporal_load((const u16x4*)(qkv + base + m * 3072));
    u16x4 uk = __builtin_nontemporal_load((const u16x4*)(qkv + base + m * 3072 + 1024));
    u16x4 uv = __builtin_nontemporal_load((const u16x4*)(qkv + base + m * 3072 + 2048));
    q[m][0] = bf2f(uq.x); q[m][1] = bf2f(uq.y); q[m][2] = bf2f(uq.z); q[m][3] = bf2f(uq.w);
    k[m][0] = bf2f(uk.x); k[m][1] = bf2f(uk.y); k[m][2] = bf2f(uk.z); k[m][3] = bf2f(uk.w);
    v[m][0] = bf2f(uv.x); v[m][1] = bf2f(uv.y); v[m][2] = bf2f(uv.z); v[m][3] = bf2f(uv.w);
  }

  float s[16];
#pragma unroll
  for (int i = 0; i < 4; ++i)
#pragma unroll
    for (int j = 0; j < 4; ++j) {
      float acc = q[i][0] * k[j][0];
      acc += q[i][1] * k[j][1];
      acc += q[i][2] * k[j][2];
      acc += q[i][3] * k[j][3];
      s[i * 4 + j] = acc;
    }
#pragma unroll
  for (int off = 1; off < 16; off <<= 1) {
#pragma unroll
    for (int t = 0; t < 16; ++t) s[t] += __shfl_xor(s[t], off);
  }

  float a[16];
#pragma unroll
  for (int i = 0; i < 4; ++i) {
    float s0 = s[i * 4 + 0] * 0.125f, s1 = s[i * 4 + 1] * 0.125f;
    float s2 = s[i * 4 + 2] * 0.125f, s3 = s[i * 4 + 3] * 0.125f;
    float m = fmaxf(fmaxf(s0, s1), fmaxf(s2, s3));
    float e0 = __expf(s0 - m), e1 = __expf(s1 - m);
    float e2 = __expf(s2 - m), e3 = __expf(s3 - m);
    float inv = 1.0f / (e0 + e1 + e2 + e3);
    a[i * 4 + 0] = e0 * inv; a[i * 4 + 1] = e1 * inv;
    a[i * 4 + 2] = e2 * inv; a[i * 4 + 3] = e3 * inv;
  }

#pragma unroll
  for (int i = 0; i < 4; ++i) {
    float c0 = a[i*4+0]*v[0][0] + a[i*4+1]*v[1][0] + a[i*4+2]*v[2][0] + a[i*4+3]*v[3][0];
    float c1 = a[i*4+0]*v[0][1] + a[i*4+1]*v[1][1] + a[i*4+2]*v[2][1] + a[i*4+3]*v[3][1];
    float c2 = a[i*4+0]*v[0][2] + a[i*4+1]*v[1][2] + a[i*4+2]*v[2][2] + a[i*4+3]*v[3][2];
    float c3 = a[i*4+0]*v[0][3] + a[i*4+1]*v[1][3] + a[i*4+2]*v[2][3] + a[i*4+3]*v[3][3];
    u16x4 o;
    o.x = f2bf(c0); o.y = f2bf(c1); o.z = f2bf(c2); o.w = f2bf(c3);
    *(u16x4*)(ctxb + (size_t)b * 4096 + i * 1024 + h0 * 64 + l * 4) = o;
  }

  int sel = l & 15;
  float val = a[0];
#pragma unroll
  for (int t = 1; t < 16; ++t) val = (sel == t) ? a[t] : val;
  __builtin_nontemporal_store(val, &attn_out[(size_t)b * 256 + h0 * 16 + l]);
}

// --------------------------- layernorm (bf16 in) ----------------------------
__global__ __launch_bounds__(256) void ln_k(const u16* __restrict__ pre,
                                            const float* __restrict__ g,
                                            const float* __restrict__ b,
                                            float* __restrict__ out) {
  int row = blockIdx.x;
  int tid = threadIdx.x;
  u16x4 u = __builtin_nontemporal_load(
      (const u16x4*)(pre + (size_t)row * 1024 + tid * 4));
  float x0 = bf2f(u.x), x1 = bf2f(u.y), x2 = bf2f(u.z), x3 = bf2f(u.w);
  float s = x0 + x1 + x2 + x3;
  float s2 = x0 * x0 + x1 * x1 + x2 * x2 + x3 * x3;
#pragma unroll
  for (int off = 32; off; off >>= 1) {
    s += __shfl_xor(s, off);
    s2 += __shfl_xor(s2, off);
  }
  __shared__ float r1[4], r2[4];
  int w = tid >> 6, lane = tid & 63;
  if (lane == 0) { r1[w] = s; r2[w] = s2; }
  __syncthreads();
  s = r1[0] + r1[1] + r1[2] + r1[3];
  s2 = r2[0] + r2[1] + r2[2] + r2[3];
  float mu = s * (1.0f / 1024.0f);
  float inv = rsqrtf(s2 * (1.0f / 1024.0f) - mu * mu + 1e-6f);
  float4 gv = *(const float4*)(g + tid * 4);
  float4 bv = *(const float4*)(b + tid * 4);
  f32x4 o;
  o.x = (x0 - mu) * inv * gv.x + bv.x;
  o.y = (x1 - mu) * inv * gv.y + bv.y;
  o.z = (x2 - mu) * inv * gv.z + bv.z;
  o.w = (x3 - mu) * inv * gv.w + bv.w;
  __builtin_nontemporal_store(o, (f32x4*)(out + (size_t)row * 1024 + tid * 4));
}

// ---------------------------------------------------------------------------
extern "C" void kernel_launch(void* const* d_in, const int* in_sizes, int n_in,
                              void* d_out, int out_size, void* d_ws,
                              size_t ws_size, hipStream_t stream) {
  const float* fcb = (const float*)d_in[14];
  const float* lng = (const float*)d_in[15];
  const float* lnb = (const float*)d_in[16];

  u16* wsb = (u16*)d_ws;
  u16* xb = wsb;                 // 62,914,560
  u16* wb = xb + 62914560;       // 24,641,536
  u16* qkv = wb + 24641536;      // 100,663,296  [b][mod][q|k|v][1024]
  u16* ctxb = qkv + 100663296;   // 33,554,432
  u16* pre = wsb;                // bf16 32768x1024 = 64MB, overlays dead xb
  float* outp = (float*)d_out;
  float* attn_out = outp + 33554432;

  static const unsigned long woff[13] = {
      0,        2097152,  4194304,   // mod0 K=2048 (q,k,v)
      6291456,  7340032,  8388608,   // mod1 K=1024
      9437184,  9961472,  10485760,  // mod2 K=512
      11010048, 15204352, 19398656,  // mod3 K=4096
      23592960};                     // fc
  static const int wn4[13] = {524288, 524288, 524288, 262144, 262144, 262144,
                              131072, 131072, 131072, 1048576, 1048576, 1048576,
                              262144};

  // K1: one conversion dispatch
  CArgs ca;
  ca.src[0] = (const float*)d_in[0];
  ca.dst[0] = 0;
  ca.n4[0] = 62914560 / 4;
  ca.blk0[0] = 0;
  int nb = ca.n4[0] / 256;
  for (int i = 0; i < 13; ++i) {
    ca.src[i + 1] = (const float*)d_in[1 + i];
    ca.dst[i + 1] = 62914560ul + woff[i];
    ca.n4[i + 1] = wn4[i];
    ca.blk0[i + 1] = nb;
    nb += (wn4[i] + 255) / 256;
  }
  convall<<<dim3(nb), 256, 0, stream>>>(ca, wsb);

  // K2: grouped QKV projections, one dispatch (4 segs x 384 blocks, LPT)
  gemm16<0><<<dim3(1536), 1024, 0, stream>>>(xb, 7680, wb, qkv, nullptr,
                                             nullptr, nullptr);

  // K3: attention
  attn_k<<<dim3(8192), 256, 0, stream>>>(qkv, ctxb, attn_out);

  // K4: FC + bias + residual -> pre-LN bf16
  gemm16<1><<<dim3(512), 1024, 0, stream>>>(ctxb, 1024, wb + 23592960, nullptr,
                                            pre, fcb, qkv);

  // K5: LayerNorm -> out
  ln_k<<<dim3(32768), 256, 0, stream>>>(pre, lng, lnb, outp);
}

// Round 15
// 666.733 us; speedup vs baseline: 1.4161x; 1.4161x over previous
//
#include <hip/hip_runtime.h>

// ---------------------------------------------------------------------------
// VariLengthInputLayer: fused multi-modality QKV + 4x4 attention + FC + LN
//   K1: merged f32->bf16 convert (one dispatch; nt input loads)
//   K2: grouped QKV GEMM, 128x256 tile, BK=32, 8 waves x 64x64 acc,
//       512 thr / ~115 VGPR -> 2 blocks/CU (4 waves/SIMD), 3-slot rotating
//       LDS (72KB), 1 barrier + counted vmcnt(3) per K-tile, XOR swizzle,
//       2D XCD chunking, LPT segment order
//   K3: attention: 4 (b,h) pairs per wave, 16-lane groups (nt qkv loads)
//   K4: FC GEMM (same engine) + bias + residual -> pre-LN bf16
//   K5: LayerNorm(1024, bf16 in) -> d_out
// ---------------------------------------------------------------------------

typedef unsigned short u16;
typedef short short8 __attribute__((ext_vector_type(8)));
typedef unsigned short u16x4 __attribute__((ext_vector_type(4)));
typedef float f32x4 __attribute__((ext_vector_type(4)));

__device__ __forceinline__ u16 f2bf(float f) {
  unsigned u = __builtin_bit_cast(unsigned, f);
  u += 0x7FFFu + ((u >> 16) & 1u);  // RNE
  return (u16)(u >> 16);
}
__device__ __forceinline__ float bf2f(u16 s) {
  return __builtin_bit_cast(float, ((unsigned)s) << 16);
}

__device__ __forceinline__ void gload16(const u16* g, u16* l) {
  __builtin_amdgcn_global_load_lds(
      (const __attribute__((address_space(1))) void*)g,
      (__attribute__((address_space(3))) void*)l, 16, 0, 0);
}

#define CFENCE asm volatile("" ::: "memory")

// --------------------------- merged f32 -> bf16 convert --------------------
struct CArgs {
  const float* src[14];
  unsigned long dst[14];
  int blk0[14];
  int n4[14];
};

__global__ __launch_bounds__(256) void convall(CArgs a, u16* __restrict__ wsb) {
  int blk = blockIdx.x;
  int s = 0;
#pragma unroll
  for (int i = 1; i < 14; ++i) s = (blk >= a.blk0[i]) ? i : s;
  int li = (blk - a.blk0[s]) * 256 + threadIdx.x;
  if (li < a.n4[s]) {
    f32x4 v = __builtin_nontemporal_load((const f32x4*)a.src[s] + li);
    u16x4 o;
    o.x = f2bf(v.x); o.y = f2bf(v.y); o.z = f2bf(v.z); o.w = f2bf(v.w);
    *((u16x4*)(wsb + a.dst[s]) + li) = o;  // plain store: GEMM re-reads this
  }
}

// --------------- 128x256 GEMM, BK=32, 3-slot LDS, 2 blocks/CU --------------
// C = A @ B^T.  A [M x K] bf16 (row stride lda), B [N x K] bf16 (K contig).
// 512 threads = 8 waves (2M x 4N); per-wave 64x64 out (acc 64 VGPR; total
// ~115 -> 4 waves/SIMD with 2 blocks/CU; LDS 72KB/block, 144/CU).
// LDS: 3 rotating slots (t%3) of {A[128][32] 8KB + B[256][32] 16KB}.
//   Rows are 64B (4 x 16B chunks); swizzle pc = kc ^ ((rw>>2)&3): a frag
//   read's 16 lanes hit 8 bank-quads x 2 lanes = conflict-free. Staging
//   writes linear LDS from inverse-swizzled global (rule #21 both-sides).
// Per K-tile t: { ldA[4] + ldB[4] (slot t%3); stage(t+2) -> slot (t+2)%3
//   [3 gload16: A x1, B x2]; lgkm0; 16 MFMA; vmcnt(3) certs stage(t+1)
//   (FIFO: 6 outstanding, drain oldest 3) BEFORE barrier = cross-wave cert;
//   barrier }.  Slot (t+2)%3 is dead: its last reads (tile t-1) drained at
//   step t-1's lgkm0, cross-wave by step t-1's barrier.
// MODE 0: grouped QKV (seg->modality, LPT), C -> qkv bf16 ldc 12288
// MODE 1: FC, C -> bf16 pre = acc + bias + residual(qkv v-slice), ldc 1024
template <int MODE>
__global__ __launch_bounds__(512, 4)
void gemmk(const u16* __restrict__ Abase, int lda,
           const u16* __restrict__ Wbase, u16* __restrict__ Cq,
           u16* __restrict__ Cpre, const float* __restrict__ bias,
           const u16* __restrict__ resid) {
  __shared__ __align__(16) u16 lds[36864];  // 72 KiB = 3 x (8KB A + 16KB B)

  const int tid = threadIdx.x;
  const int w = tid >> 6, lane = tid & 63;
  const int lr = lane & 15, lk = lane >> 4;
  const int wm = w >> 2, wn = w & 3;  // 2x4 wave grid

  int K, nt, bx, by, coff;
  const u16 *A, *B;
  if (MODE == 0) {
    int seg = blockIdx.x / 768;  // LPT: longest K first
    int r = blockIdx.x % 768;
    // XCD chunking: xcd = r%8 (hw round-robin, 768%8==0 bijective);
    // each XCD: 8by x 12bx chunk, bx fastest (A panels XCD-L2-resident)
    int xcd = r & 7;
    int slot = r >> 3;           // 0..95
    by = xcd * 8 + slot / 12;    // 0..63
    bx = slot % 12;
    K = 4096 >> seg; nt = 128 >> seg;
    int xo, wo, mod;
    switch (seg) {
      case 0:  xo = 3584; wo = 11010048; mod = 3; break;
      case 1:  xo = 0;    wo = 0;        mod = 0; break;
      case 2:  xo = 2048; wo = 6291456;  mod = 1; break;
      default: xo = 3072; wo = 9437184;  mod = 2; break;
    }
    coff = mod * 3072;
    A = Abase + xo;
    B = Wbase + wo;
  } else {
    int xcd = blockIdx.x & 7;    // 1024%8==0 bijective
    int slot = blockIdx.x >> 3;  // 0..127
    by = xcd * 32 + (slot >> 2); // 0..255
    bx = slot & 3;
    K = 1024; nt = 32; coff = 0;
    A = Abase; B = Wbase;
  }
  const size_t brow = (size_t)by * 128;
  const int bcol = bx * 256;
  const u16* Ab = A + brow * (size_t)lda;
  const u16* Bb = B + (size_t)bcol * (size_t)K;

  f32x4 acc[4][4];
#pragma unroll
  for (int i = 0; i < 4; ++i)
#pragma unroll
    for (int j = 0; j < 4; ++j) acc[i][j] = (f32x4){0.f, 0.f, 0.f, 0.f};

  // stage slot (p%3): A 1 pass + B 2 passes, 3 gload16/thread
  auto stage = [&](int p) {
    const int sb = (p % 3) * 24576;  // slot base, bytes
    const int k0 = p * 32;
    {
      int s = tid * 16;                          // 0..8191
      int rw = s >> 6;                           // A row 0..127
      int ck = ((s >> 4) & 3) ^ ((rw >> 2) & 3);
      gload16(Ab + (size_t)rw * lda + k0 + ck * 8, &lds[(sb + s) >> 1]);
    }
#pragma unroll
    for (int l = 0; l < 2; ++l) {
      int s = l * 8192 + tid * 16;               // 0..16383
      int rw = s >> 6;                           // B row (C col) 0..255
      int ck = ((s >> 4) & 3) ^ ((rw >> 2) & 3);
      gload16(Bb + (size_t)rw * (size_t)K + k0 + ck * 8,
              &lds[(sb + 8192 + s) >> 1]);
    }
  };

  auto ldA = [&](int t, short8* dst) {  // 4 frags
    const u16* lp = lds + ((t % 3) * 24576 >> 1);
#pragma unroll
    for (int mi = 0; mi < 4; ++mi) {
      int rw = wm * 64 + mi * 16 + lr;
      int pc = lk ^ ((rw >> 2) & 3);
      dst[mi] = *(const short8*)(lp + rw * 32 + pc * 8);
    }
  };
  auto ldB = [&](int t, short8* dst) {  // 4 frags
    const u16* lp = lds + (((t % 3) * 24576 + 8192) >> 1);
#pragma unroll
    for (int ni = 0; ni < 4; ++ni) {
      int rw = wn * 64 + ni * 16 + lr;
      int pc = lk ^ ((rw >> 2) & 3);
      dst[ni] = *(const short8*)(lp + rw * 32 + pc * 8);
    }
  };

  // prologue: stage slots 0,1 (6 loads); vmcnt(3) certs slot 0; barrier
  stage(0); stage(1);
  asm volatile("s_waitcnt vmcnt(3)" ::: "memory");
  __builtin_amdgcn_s_barrier();
  CFENCE;

#pragma unroll 1
  for (int t = 0; t < nt; ++t) {
    short8 af[4], bf4[4];
    ldA(t, af);
    ldB(t, bf4);
    if (t + 2 < nt) stage(t + 2);
    CFENCE;
    asm volatile("s_waitcnt lgkmcnt(0)" ::: "memory");
    __builtin_amdgcn_sched_barrier(0);
    __builtin_amdgcn_s_setprio(1);
#pragma unroll
    for (int mi = 0; mi < 4; ++mi)
#pragma unroll
      for (int ni = 0; ni < 4; ++ni)
        acc[mi][ni] = __builtin_amdgcn_mfma_f32_16x16x32_bf16(
            af[mi], bf4[ni], acc[mi][ni], 0, 0, 0);
    __builtin_amdgcn_s_setprio(0);
    CFENCE;
    if (t + 1 < nt) {
      // cert stage(t+1): oldest 3 of (up to) 6 outstanding; never 0 mid-loop
      if (t + 2 < nt) asm volatile("s_waitcnt vmcnt(3)" ::: "memory");
      else            asm volatile("s_waitcnt vmcnt(0)" ::: "memory");
      __builtin_amdgcn_s_barrier();
      CFENCE;
    }
  }

  // epilogue: C/D layout col=lane&15, row=(lane>>4)*4+j
  if (MODE == 0) {
#pragma unroll
    for (int mi = 0; mi < 4; ++mi)
#pragma unroll
      for (int ni = 0; ni < 4; ++ni) {
        const int c = coff + bcol + wn * 64 + ni * 16 + lr;
#pragma unroll
        for (int j = 0; j < 4; ++j) {
          size_t r = brow + wm * 64 + mi * 16 + lk * 4 + j;
          Cq[r * 12288 + c] = f2bf(acc[mi][ni][j]);
        }
      }
  } else {
#pragma unroll
    for (int mi = 0; mi < 4; ++mi)
#pragma unroll
      for (int ni = 0; ni < 4; ++ni) {
        const int c = bcol + wn * 64 + ni * 16 + lr;
        const float bs = bias[c];
#pragma unroll
        for (int j = 0; j < 4; ++j) {
          size_t r = brow + wm * 64 + mi * 16 + lk * 4 + j;
          size_t ridx = (r >> 2) * 12288 + (r & 3) * 3072 + 2048 + c;
          Cpre[r * 1024 + c] = f2bf(acc[mi][ni][j] + bs + bf2f(resid[ridx]));
        }
      }
  }
}

// --------------------------- attention ------------------------------------
__global__ __launch_bounds__(256) void attn_k(const u16* __restrict__ qkv,
                                              u16* __restrict__ ctxb,
                                              float* __restrict__ attn_out) {
  const int tid = threadIdx.x;
  const int l = tid & 63;
  const int wg = blockIdx.x * 4 + (tid >> 6);
  const int b = wg >> 2;
  const int h0 = (wg & 3) << 2;
  const size_t base = (size_t)b * 12288 + h0 * 64 + l * 4;

  float q[4][4], k[4][4], v[4][4];
#pragma unroll
  for (int m = 0; m < 4; ++m) {
    u16x4 uq = __builtin_nontemporal_load((const u16x4*)(qkv + base + m * 3072));
    u16x4 uk = __builtin_nontemporal_load((const u16x4*)(qkv + base + m * 3072 + 1024));
    u16x4 uv = __builtin_nontemporal_load((const u16x4*)(qkv + base + m * 3072 + 2048));
    q[m][0] = bf2f(uq.x); q[m][1] = bf2f(uq.y); q[m][2] = bf2f(uq.z); q[m][3] = bf2f(uq.w);
    k[m][0] = bf2f(uk.x); k[m][1] = bf2f(uk.y); k[m][2] = bf2f(uk.z); k[m][3] = bf2f(uk.w);
    v[m][0] = bf2f(uv.x); v[m][1] = bf2f(uv.y); v[m][2] = bf2f(uv.z); v[m][3] = bf2f(uv.w);
  }

  float s[16];
#pragma unroll
  for (int i = 0; i < 4; ++i)
#pragma unroll
    for (int j = 0; j < 4; ++j) {
      float acc = q[i][0] * k[j][0];
      acc += q[i][1] * k[j][1];
      acc += q[i][2] * k[j][2];
      acc += q[i][3] * k[j][3];
      s[i * 4 + j] = acc;
    }
#pragma unroll
  for (int off = 1; off < 16; off <<= 1) {
#pragma unroll
    for (int t = 0; t < 16; ++t) s[t] += __shfl_xor(s[t], off);
  }

  float a[16];
#pragma unroll
  for (int i = 0; i < 4; ++i) {
    float s0 = s[i * 4 + 0] * 0.125f, s1 = s[i * 4 + 1] * 0.125f;
    float s2 = s[i * 4 + 2] * 0.125f, s3 = s[i * 4 + 3] * 0.125f;
    float m = fmaxf(fmaxf(s0, s1), fmaxf(s2, s3));
    float e0 = __expf(s0 - m), e1 = __expf(s1 - m);
    float e2 = __expf(s2 - m), e3 = __expf(s3 - m);
    float inv = 1.0f / (e0 + e1 + e2 + e3);
    a[i * 4 + 0] = e0 * inv; a[i * 4 + 1] = e1 * inv;
    a[i * 4 + 2] = e2 * inv; a[i * 4 + 3] = e3 * inv;
  }

#pragma unroll
  for (int i = 0; i < 4; ++i) {
    float c0 = a[i*4+0]*v[0][0] + a[i*4+1]*v[1][0] + a[i*4+2]*v[2][0] + a[i*4+3]*v[3][0];
    float c1 = a[i*4+0]*v[0][1] + a[i*4+1]*v[1][1] + a[i*4+2]*v[2][1] + a[i*4+3]*v[3][1];
    float c2 = a[i*4+0]*v[0][2] + a[i*4+1]*v[1][2] + a[i*4+2]*v[2][2] + a[i*4+3]*v[3][2];
    float c3 = a[i*4+0]*v[0][3] + a[i*4+1]*v[1][3] + a[i*4+2]*v[2][3] + a[i*4+3]*v[3][3];
    u16x4 o;
    o.x = f2bf(c0); o.y = f2bf(c1); o.z = f2bf(c2); o.w = f2bf(c3);
    *(u16x4*)(ctxb + (size_t)b * 4096 + i * 1024 + h0 * 64 + l * 4) = o;
  }

  int sel = l & 15;
  float val = a[0];
#pragma unroll
  for (int t = 1; t < 16; ++t) val = (sel == t) ? a[t] : val;
  __builtin_nontemporal_store(val, &attn_out[(size_t)b * 256 + h0 * 16 + l]);
}

// --------------------------- layernorm (bf16 in) ----------------------------
__global__ __launch_bounds__(256) void ln_k(const u16* __restrict__ pre,
                                            const float* __restrict__ g,
                                            const float* __restrict__ b,
                                            float* __restrict__ out) {
  int row = blockIdx.x;
  int tid = threadIdx.x;
  u16x4 u = __builtin_nontemporal_load(
      (const u16x4*)(pre + (size_t)row * 1024 + tid * 4));
  float x0 = bf2f(u.x), x1 = bf2f(u.y), x2 = bf2f(u.z), x3 = bf2f(u.w);
  float s = x0 + x1 + x2 + x3;
  float s2 = x0 * x0 + x1 * x1 + x2 * x2 + x3 * x3;
#pragma unroll
  for (int off = 32; off; off >>= 1) {
    s += __shfl_xor(s, off);
    s2 += __shfl_xor(s2, off);
  }
  __shared__ float r1[4], r2[4];
  int w = tid >> 6, lane = tid & 63;
  if (lane == 0) { r1[w] = s; r2[w] = s2; }
  __syncthreads();
  s = r1[0] + r1[1] + r1[2] + r1[3];
  s2 = r2[0] + r2[1] + r2[2] + r2[3];
  float mu = s * (1.0f / 1024.0f);
  float inv = rsqrtf(s2 * (1.0f / 1024.0f) - mu * mu + 1e-6f);
  float4 gv = *(const float4*)(g + tid * 4);
  float4 bv = *(const float4*)(b + tid * 4);
  f32x4 o;
  o.x = (x0 - mu) * inv * gv.x + bv.x;
  o.y = (x1 - mu) * inv * gv.y + bv.y;
  o.z = (x2 - mu) * inv * gv.z + bv.z;
  o.w = (x3 - mu) * inv * gv.w + bv.w;
  __builtin_nontemporal_store(o, (f32x4*)(out + (size_t)row * 1024 + tid * 4));
}

// ---------------------------------------------------------------------------
extern "C" void kernel_launch(void* const* d_in, const int* in_sizes, int n_in,
                              void* d_out, int out_size, void* d_ws,
                              size_t ws_size, hipStream_t stream) {
  const float* fcb = (const float*)d_in[14];
  const float* lng = (const float*)d_in[15];
  const float* lnb = (const float*)d_in[16];

  u16* wsb = (u16*)d_ws;
  u16* xb = wsb;                 // 62,914,560
  u16* wb = xb + 62914560;       // 24,641,536
  u16* qkv = wb + 24641536;      // 100,663,296  [b][mod][q|k|v][1024]
  u16* ctxb = qkv + 100663296;   // 33,554,432
  u16* pre = wsb;                // bf16 32768x1024 = 64MB, overlays dead xb
  float* outp = (float*)d_out;
  float* attn_out = outp + 33554432;

  static const unsigned long woff[13] = {
      0,        2097152,  4194304,   // mod0 K=2048 (q,k,v)
      6291456,  7340032,  8388608,   // mod1 K=1024
      9437184,  9961472,  10485760,  // mod2 K=512
      11010048, 15204352, 19398656,  // mod3 K=4096
      23592960};                     // fc
  static const int wn4[13] = {524288, 524288, 524288, 262144, 262144, 262144,
                              131072, 131072, 131072, 1048576, 1048576, 1048576,
                              262144};

  // K1: one conversion dispatch
  CArgs ca;
  ca.src[0] = (const float*)d_in[0];
  ca.dst[0] = 0;
  ca.n4[0] = 62914560 / 4;
  ca.blk0[0] = 0;
  int nb = ca.n4[0] / 256;
  for (int i = 0; i < 13; ++i) {
    ca.src[i + 1] = (const float*)d_in[1 + i];
    ca.dst[i + 1] = 62914560ul + woff[i];
    ca.n4[i + 1] = wn4[i];
    ca.blk0[i + 1] = nb;
    nb += (wn4[i] + 255) / 256;
  }
  convall<<<dim3(nb), 256, 0, stream>>>(ca, wsb);

  // K2: grouped QKV projections, one dispatch (4 segs x 768 blocks, LPT)
  gemmk<0><<<dim3(3072), 512, 0, stream>>>(xb, 7680, wb, qkv, nullptr,
                                           nullptr, nullptr);

  // K3: attention
  attn_k<<<dim3(8192), 256, 0, stream>>>(qkv, ctxb, attn_out);

  // K4: FC + bias + residual -> pre-LN bf16
  gemmk<1><<<dim3(1024), 512, 0, stream>>>(ctxb, 1024, wb + 23592960, nullptr,
                                           pre, fcb, qkv);

  // K5: LayerNorm -> out
  ln_k<<<dim3(32768), 256, 0, stream>>>(pre, lng, lnb, outp);
}